// Round 13
// baseline (807.069 us; speedup 1.0000x reference)
//
#include <hip/hip_runtime.h>
#include <hip/hip_bf16.h>

#define NTOK 8192
#define DIM 1024
#define HID 2816
#define NE 8
#define NSLOT (NTOK*2)
#define BM 256
#define BK 32
#define MAXMT (NSLOT/BM + NE)   // 72 worst-case M-tiles @ BM=256

typedef float f32x4 __attribute__((ext_vector_type(4)));
typedef __bf16 bf16x8 __attribute__((ext_vector_type(8)));
typedef __bf16 bf16x4 __attribute__((ext_vector_type(4)));

#define MFMA(a,b,c) __builtin_amdgcn_mfma_f32_16x16x32_bf16(a,b,c,0,0,0)
// element index in a linear [rows][32] bf16 tile, XOR bank swizzle (R2-proven: 0 conflicts)
#define SWZ(r,g) (((r)<<5) + ((((g) ^ (((r)>>1)&3)))<<3))

__device__ __forceinline__ void cvt_st8(__bf16* d, f32x4 a, f32x4 b){
  bf16x8 v;
  v[0]=(__bf16)a.x; v[1]=(__bf16)a.y; v[2]=(__bf16)a.z; v[3]=(__bf16)a.w;
  v[4]=(__bf16)b.x; v[5]=(__bf16)b.y; v[6]=(__bf16)b.z; v[7]=(__bf16)b.w;
  *reinterpret_cast<bf16x8*>(d) = v;
}
__device__ __forceinline__ void gld_lds16(const void* g, void* l){
  __builtin_amdgcn_global_load_lds(
    (const __attribute__((address_space(1))) void*)g,
    (__attribute__((address_space(3))) void*)l, 16, 0, 0);
}
__device__ __forceinline__ int xcd_map(int orig, int nwg){
  int q = nwg>>3, rr = nwg&7, x = orig&7, o = orig>>3;
  return (x<rr ? x*(q+1) : rr*(q+1)+(x-rr)*q) + o;
}

// ---------------- fused fp32->bf16 conversion (also zeroes cnt) ----------------
__global__ __launch_bounds__(256) void k_cvt3(
    const float* __restrict__ s1, const float* __restrict__ s3,
    const float* __restrict__ s2, __bf16* __restrict__ d1,
    __bf16* __restrict__ d3, __bf16* __restrict__ d2, int* __restrict__ cnt)
{
  if(blockIdx.x==0 && threadIdx.x < NE) cnt[threadIdx.x] = 0;
  const int PB = (NE*HID*DIM/8)/256;     // 11264 blocks per tensor
  int seg = blockIdx.x / PB;
  int i   = (blockIdx.x % PB)*256 + threadIdx.x;
  const float* src = (seg==0) ? s1 : (seg==1) ? s3 : s2;
  __bf16*      dst = (seg==0) ? d1 : (seg==1) ? d3 : d2;
  const f32x4* s = reinterpret_cast<const f32x4*>(src) + (size_t)i*2;
  f32x4 a = s[0], b = s[1];
  cvt_st8(dst + (size_t)i*8, a, b);
}

// ---- gating: lane-parallel f64 dots (R7-proven); also zeroes this block's y rows ----
__global__ __launch_bounds__(256) void k_gate(const float* __restrict__ x,
    const float* __restrict__ gw, int* __restrict__ idxs,
    float* __restrict__ wt, int* __restrict__ cnt, __bf16* __restrict__ xb,
    float* __restrict__ y)
{
  __shared__ double part[8][8][4];
  __shared__ double lg[8][8];

  int tid = threadIdx.x;
  int tl = tid>>5, e = (tid>>2)&7, q = tid&3;
  int t  = blockIdx.x*8 + tl;

  const f32x4* x4 = reinterpret_cast<const f32x4*>(x)  + (size_t)t*256 + q*64;
  const f32x4* g4 = reinterpret_cast<const f32x4*>(gw) + e*256 + q*64;

  double s0 = 0.0, s1 = 0.0;
#pragma unroll 4
  for(int j=0;j<64;j+=2){
    f32x4 a0 = x4[j],   b0 = g4[j];
    f32x4 a1 = x4[j+1], b1 = g4[j+1];
    s0 += (double)a0.x*b0.x + (double)a0.y*b0.y
        + (double)a0.z*b0.z + (double)a0.w*b0.w;
    s1 += (double)a1.x*b1.x + (double)a1.y*b1.y
        + (double)a1.z*b1.z + (double)a1.w*b1.w;
  }
  part[tl][e][q] = s0 + s1;
  __syncthreads();
  if(q==0)
    lg[tl][e] = part[tl][e][0] + part[tl][e][1] + part[tl][e][2] + part[tl][e][3];
  __syncthreads();

  if(tid < 8){
    int tt = blockIdx.x*8 + tid;
    int i1=0; double m1=lg[tid][0];
#pragma unroll
    for(int k=1;k<NE;k++) if(lg[tid][k]>m1){ m1=lg[tid][k]; i1=k; }
    int i2=-1; double m2=-1e300;
#pragma unroll
    for(int k=0;k<NE;k++) if(k!=i1 && lg[tid][k]>m2){ m2=lg[tid][k]; i2=k; }
    float e2 = __expf((float)(m2-m1));
    float w0 = 1.f/(1.f+e2);
    idxs[2*tt]=i1; idxs[2*tt+1]=i2;
    wt[2*tt]=w0;   wt[2*tt+1]=e2*w0;
    atomicAdd(&cnt[i1],1); atomicAdd(&cnt[i2],1);
  }

  // bf16 copy of the block's 8 x-rows
  const f32x4* xs = reinterpret_cast<const f32x4*>(x) + (size_t)blockIdx.x*2048;
  __bf16* xo = xb + (size_t)blockIdx.x*8192;
#pragma unroll
  for(int k=0;k<4;k++){
    int c = k*256 + tid;
    cvt_st8(xo + (size_t)c*8, xs[2*c], xs[2*c+1]);
  }

  // zero this block's 8 y rows, ready for ffn2 atomics
  f32x4* yz = reinterpret_cast<f32x4*>(y) + (size_t)blockIdx.x*2048;
#pragma unroll
  for(int k=0;k<8;k++)
    yz[k*256 + tid] = f32x4{0.f,0.f,0.f,0.f};
}

__global__ void k_prep(const int* __restrict__ cnt, int* __restrict__ off,
                       int* __restrict__ mtp, int* __restrict__ cursor)
{
  if(threadIdx.x==0){
    int o=0, m=0; off[0]=0; mtp[0]=0;
    for(int e=0;e<NE;e++){
      cursor[e]=o; o += cnt[e]; off[e+1]=o;
      m += (cnt[e]+BM-1)/BM;  mtp[e+1]=m;
    }
  }
}

__global__ __launch_bounds__(256) void k_scatter(const int* __restrict__ idxs,
    int* __restrict__ cursor, int* __restrict__ order)
{
  int t = blockIdx.x*blockDim.x + threadIdx.x;
#pragma unroll
  for(int k=0;k<2;k++){
    int s = 2*t+k;
    int e = idxs[s];
    int p = atomicAdd(&cursor[e],1);
    order[p]=s;
  }
}

// ======== FFN1: 256x128x2 tile, BK=32, 512 thr, 2-phase (split for visibility) ========
// Issued traffic 2.24 GB -> 1.58 GB vs BM=128. LDS 64KB -> 2 blk/CU.
#define NT_H 11
__global__ __launch_bounds__(512) void k_ffn1(
    const __bf16* __restrict__ xb, const __bf16* __restrict__ w1b,
    const __bf16* __restrict__ w3b, const int* __restrict__ off,
    const int* __restrict__ mtp, const int* __restrict__ order,
    __bf16* __restrict__ h, int nt_off)
{
  __shared__ __align__(16) __bf16 lA [2][BM*BK];    // 16 KB per buf
  __shared__ __align__(16) __bf16 lB1[2][128*BK];   // 8 KB per buf
  __shared__ __align__(16) __bf16 lB3[2][128*BK];

  int wg = xcd_map(blockIdx.x, MAXMT*NT_H);
  int mt = wg / NT_H, nt = nt_off + wg % NT_H;
  if (mt >= mtp[NE]) return;
  int e = 0;
  while (mt >= mtp[e+1]) e++;
  int row0    = off[e] + (mt - mtp[e])*BM;
  int row_end = off[e+1];
  int n0      = nt*128;

  int tid = threadIdx.x, lane = tid&63, wave = tid>>6;
  int sr = tid>>2;                       // 0..127
  int scol = ((tid&3) ^ ((sr>>1)&3))<<3; // same phase for sr+128 (128%8==0)
  int ar0 = min(row0 + sr,       row_end-1);
  int ar1 = min(row0 + sr + 128, row_end-1);
  const __bf16* a0  = xb  + (size_t)(order[ar0]>>1)*DIM + scol;
  const __bf16* a1  = xb  + (size_t)(order[ar1]>>1)*DIM + scol;
  const __bf16* gB1 = w1b + (size_t)e*HID*DIM + (size_t)(n0+sr)*DIM + scol;
  const __bf16* gB3 = w3b + (size_t)e*HID*DIM + (size_t)(n0+sr)*DIM + scol;
  int ldso = wave<<9;                    // wave * 512 elements (1KB)

  int wm = wave>>2, wn = wave&3;         // 2x4 wave grid; wave tile 128(M)x32(N) x2 tensors
  int fr = lane&15, gq = lane>>4;

  f32x4 acc1[8][2], acc3[8][2];
#pragma unroll
  for(int m=0;m<8;m++)
#pragma unroll
    for(int n=0;n<2;n++){ acc1[m][n]=f32x4{0.f,0.f,0.f,0.f}; acc3[m][n]=f32x4{0.f,0.f,0.f,0.f}; }

#define F1_STG(b, kt_) { \
    gld_lds16(a0  + (kt_)*BK, &lA [b][ldso]); \
    gld_lds16(a1  + (kt_)*BK, &lA [b][4096+ldso]); \
    gld_lds16(gB1 + (kt_)*BK, &lB1[b][ldso]); \
    gld_lds16(gB3 + (kt_)*BK, &lB3[b][ldso]); }

  F1_STG(0, 0);
  __syncthreads();

  const int NK = DIM/BK;                 // 32
  int buf=0;
  for(int kt=0; kt<NK; kt++){
    if(kt+1<NK) F1_STG(buf^1, kt+1);
    bf16x8 av[8], bv[2], cv[2];
#pragma unroll
    for(int m=0;m<8;m++) av[m]=*reinterpret_cast<const bf16x8*>(&lA[buf][SWZ(wm*128+m*16+fr, gq)]);
#pragma unroll
    for(int n=0;n<2;n++){
      bv[n]=*reinterpret_cast<const bf16x8*>(&lB1[buf][SWZ(wn*32+n*16+fr, gq)]);
      cv[n]=*reinterpret_cast<const bf16x8*>(&lB3[buf][SWZ(wn*32+n*16+fr, gq)]);
    }
#pragma unroll
    for(int m=0;m<8;m++)
#pragma unroll
      for(int n=0;n<2;n++){
        acc1[m][n]=MFMA(av[m],bv[n],acc1[m][n]);
        acc3[m][n]=MFMA(av[m],cv[n],acc3[m][n]);
      }
    __syncthreads();
    buf^=1;
  }
#undef F1_STG

#pragma unroll
  for(int m=0;m<8;m++){
    int rbase = row0 + wm*128 + m*16 + (gq<<2);
#pragma unroll
    for(int r=0;r<4;r++){
      if(rbase+r < row_end){
        __bf16* hp = h + (size_t)(rbase+r)*HID + n0 + wn*32 + fr;
#pragma unroll
        for(int n=0;n<2;n++){
          float u = acc1[m][n][r], v = acc3[m][n][r];
          hp[n*16] = (__bf16)( (u/(1.f+__expf(-u))) * v );
        }
      }
    }
  }
}

// ======== FFN2: 256x128 tile, BK=32, 512 thr, 2-phase, atomic combine epilogue ========
// Issued traffic 1.52 GB -> 1.25 GB. LDS 48KB.
__global__ __launch_bounds__(512) void k_ffn2(
    const __bf16* __restrict__ h, const __bf16* __restrict__ w2b,
    const int* __restrict__ off, const int* __restrict__ mtp,
    const int* __restrict__ order, const float* __restrict__ wt,
    float* __restrict__ y)
{
  __shared__ __align__(16) __bf16 lA[2][BM*BK];     // 16 KB per buf
  __shared__ __align__(16) __bf16 lB[2][128*BK];    // 8 KB per buf

  const int NT = DIM/128;                // 8
  int wg = xcd_map(blockIdx.x, MAXMT*NT);
  int mt = wg / NT, nt = wg % NT;
  if (mt >= mtp[NE]) return;
  int e = 0;
  while (mt >= mtp[e+1]) e++;
  int row0    = off[e] + (mt - mtp[e])*BM;
  int row_end = off[e+1];
  int n0      = nt*128;

  int tid = threadIdx.x, lane = tid&63, wave = tid>>6;  // 8 waves
  int sr = tid>>2;                       // 0..127
  int scol = ((tid&3) ^ ((sr>>1)&3))<<3;
  int hr0 = min(row0 + sr,       NSLOT-1);
  int hr1 = min(row0 + sr + 128, NSLOT-1);
  const __bf16* gA0 = h   + (size_t)hr0*HID + scol;
  const __bf16* gA1 = h   + (size_t)hr1*HID + scol;
  const __bf16* gB  = w2b + (size_t)e*DIM*HID + (size_t)(n0+sr)*HID + scol;
  int ldso = wave<<9;

  int wm = wave>>1, wn = wave&1;         // 4x2 wave grid; wave tile 64(M)x64(N)
  int fr = lane&15, gq = lane>>4;

  f32x4 acc[4][4];
#pragma unroll
  for(int m=0;m<4;m++)
#pragma unroll
    for(int n=0;n<4;n++) acc[m][n]=f32x4{0.f,0.f,0.f,0.f};

#define F2_STG(b, kt_) { \
    gld_lds16(gA0 + (kt_)*BK, &lA[b][ldso]); \
    gld_lds16(gA1 + (kt_)*BK, &lA[b][4096+ldso]); \
    gld_lds16(gB  + (kt_)*BK, &lB[b][ldso]); }

  F2_STG(0, 0);
  __syncthreads();

  const int NK = HID/BK;                 // 88
  int buf=0;
  for(int kt=0; kt<NK; kt++){
    if(kt+1<NK) F2_STG(buf^1, kt+1);
    bf16x8 av[4], bv[4];
#pragma unroll
    for(int m=0;m<4;m++) av[m]=*reinterpret_cast<const bf16x8*>(&lA[buf][SWZ(wm*64+m*16+fr, gq)]);
#pragma unroll
    for(int n=0;n<4;n++) bv[n]=*reinterpret_cast<const bf16x8*>(&lB[buf][SWZ(wn*64+n*16+fr, gq)]);
#pragma unroll
    for(int m=0;m<4;m++)
#pragma unroll
      for(int n=0;n<4;n++)
        acc[m][n]=MFMA(av[m],bv[n],acc[m][n]);
    __syncthreads();
    buf^=1;
  }
#undef F2_STG

  // epilogue: weighted atomic combine into y (2 commutative addends/element)
#pragma unroll
  for(int m=0;m<4;m++){
    int rbase = row0 + wm*64 + m*16 + (gq<<2);
#pragma unroll
    for(int r=0;r<4;r++){
      int p = rbase + r;
      if(p < row_end){
        int s = order[p];
        float wv = wt[s];
        float* yp = y + (size_t)(s>>1)*DIM + n0 + wn*64 + fr;
#pragma unroll
        for(int n=0;n<4;n++) atomicAdd(&yp[n*16], wv*acc[m][n][r]);
      }
    }
  }
}

// ---------------- launch ----------------
extern "C" void kernel_launch(void* const* d_in, const int* in_sizes, int n_in,
                              void* d_out, int out_size, void* d_ws, size_t ws_size,
                              hipStream_t stream)
{
  const float* x  = (const float*)d_in[0];
  const float* gw = (const float*)d_in[1];
  const float* w1 = (const float*)d_in[2];
  const float* w3 = (const float*)d_in[3];
  const float* w2 = (const float*)d_in[4];
  float* y = (float*)d_out;
  char* ws = (char*)d_ws;

  int*   cnt    = (int*)(ws + 0);
  int*   off    = (int*)(ws + 64);
  int*   mtp    = (int*)(ws + 128);
  int*   cursor = (int*)(ws + 256);
  int*   idxs   = (int*)(ws + 320);
  float* wt     = (float*)(ws + 320 + 65536);
  int*   order  = (int*)(ws + 320 + 2*65536);
  __bf16* h     = (__bf16*)(ws + 262464);
  __bf16* xb    = (__bf16*)(ws + 262464 + 92274688ull);
  __bf16* w1b   = (__bf16*)(ws + 262464 + 92274688ull + 16777216ull);
  __bf16* w3b   = (__bf16*)(ws + 262464 + 92274688ull + 16777216ull + 46137344ull);
  __bf16* w2b   = (__bf16*)(ws + 262464 + 92274688ull + 16777216ull + 2*46137344ull);

  const int PB = (NE*HID*DIM/8)/256;     // 11264 blocks per tensor

  k_cvt3   <<<3*PB, 256, 0, stream>>>(w1, w3, w2, w1b, w3b, w2b, cnt);
  k_gate   <<<NTOK/8, 256, 0, stream>>>(x, gw, idxs, wt, cnt, xb, y);
  k_prep   <<<1, 64, 0, stream>>>(cnt, off, mtp, cursor);
  k_scatter<<<NTOK/256, 256, 0, stream>>>(idxs, cursor, order);
  k_ffn1   <<<MAXMT*NT_H, 512, 0, stream>>>(xb, w1b, w3b, off, mtp, order, h, 0);
  k_ffn1   <<<MAXMT*NT_H, 512, 0, stream>>>(xb, w1b, w3b, off, mtp, order, h, NT_H);
  k_ffn2   <<<MAXMT*(DIM/128), 512, 0, stream>>>(h, w2b, off, mtp, order, wt, y);
}

// Round 14
// 677.993 us; speedup vs baseline: 1.1904x; 1.1904x over previous
//
#include <hip/hip_runtime.h>
#include <hip/hip_bf16.h>

#define NTOK 8192
#define DIM 1024
#define HID 2816
#define NE 8
#define NSLOT (NTOK*2)
#define BM 128
#define BK 32
#define MAXMT (NSLOT/BM + NE)   // 136 worst-case M-tiles @ BM=128

typedef float f32x4 __attribute__((ext_vector_type(4)));
typedef __bf16 bf16x8 __attribute__((ext_vector_type(8)));
typedef __bf16 bf16x4 __attribute__((ext_vector_type(4)));

#define MFMA(a,b,c) __builtin_amdgcn_mfma_f32_16x16x32_bf16(a,b,c,0,0,0)
// element index in a linear [rows][32] bf16 tile, XOR bank swizzle (R2-proven: 0 conflicts)
#define SWZ(r,g) (((r)<<5) + ((((g) ^ (((r)>>1)&3)))<<3))

__device__ __forceinline__ void cvt_st8(__bf16* d, f32x4 a, f32x4 b){
  bf16x8 v;
  v[0]=(__bf16)a.x; v[1]=(__bf16)a.y; v[2]=(__bf16)a.z; v[3]=(__bf16)a.w;
  v[4]=(__bf16)b.x; v[5]=(__bf16)b.y; v[6]=(__bf16)b.z; v[7]=(__bf16)b.w;
  *reinterpret_cast<bf16x8*>(d) = v;
}
__device__ __forceinline__ void gld_lds16(const void* g, void* l){
  __builtin_amdgcn_global_load_lds(
    (const __attribute__((address_space(1))) void*)g,
    (__attribute__((address_space(3))) void*)l, 16, 0, 0);
}
__device__ __forceinline__ int xcd_map(int orig, int nwg){
  int q = nwg>>3, rr = nwg&7, x = orig&7, o = orig>>3;
  return (x<rr ? x*(q+1) : rr*(q+1)+(x-rr)*q) + o;
}

// ---------------- fused fp32->bf16 conversion (fat threads: 16 f32 each) ----------------
#define CVTPB (NE*HID*DIM/16/256)   // 5632 blocks per tensor
__global__ __launch_bounds__(256) void k_cvt3(
    const float* __restrict__ s1, const float* __restrict__ s3,
    const float* __restrict__ s2, __bf16* __restrict__ d1,
    __bf16* __restrict__ d3, __bf16* __restrict__ d2, int* __restrict__ cnt)
{
  if(blockIdx.x==0 && threadIdx.x < NE) cnt[threadIdx.x] = 0;
  int seg = blockIdx.x / CVTPB;
  size_t i = (size_t)(blockIdx.x % CVTPB)*256 + threadIdx.x;   // unit of 16 f32
  const float* src = (seg==0) ? s1 : (seg==1) ? s3 : s2;
  __bf16*      dst = (seg==0) ? d1 : (seg==1) ? d3 : d2;
  const f32x4* s = reinterpret_cast<const f32x4*>(src) + i*4;
  f32x4 a = s[0], b = s[1], c = s[2], d = s[3];
  cvt_st8(dst + i*16,     a, b);
  cvt_st8(dst + i*16 + 8, c, d);
}

// ---- gating: lane-parallel f64 dots (R7-proven); also zeroes this block's y rows ----
__global__ __launch_bounds__(256) void k_gate(const float* __restrict__ x,
    const float* __restrict__ gw, int* __restrict__ idxs,
    float* __restrict__ wt, int* __restrict__ cnt, __bf16* __restrict__ xb,
    float* __restrict__ y)
{
  __shared__ double part[8][8][4];
  __shared__ double lg[8][8];

  int tid = threadIdx.x;
  int tl = tid>>5, e = (tid>>2)&7, q = tid&3;
  int t  = blockIdx.x*8 + tl;

  const f32x4* x4 = reinterpret_cast<const f32x4*>(x)  + (size_t)t*256 + q*64;
  const f32x4* g4 = reinterpret_cast<const f32x4*>(gw) + e*256 + q*64;

  double s0 = 0.0, s1 = 0.0;
#pragma unroll 4
  for(int j=0;j<64;j+=2){
    f32x4 a0 = x4[j],   b0 = g4[j];
    f32x4 a1 = x4[j+1], b1 = g4[j+1];
    s0 += (double)a0.x*b0.x + (double)a0.y*b0.y
        + (double)a0.z*b0.z + (double)a0.w*b0.w;
    s1 += (double)a1.x*b1.x + (double)a1.y*b1.y
        + (double)a1.z*b1.z + (double)a1.w*b1.w;
  }
  part[tl][e][q] = s0 + s1;
  __syncthreads();
  if(q==0)
    lg[tl][e] = part[tl][e][0] + part[tl][e][1] + part[tl][e][2] + part[tl][e][3];
  __syncthreads();

  if(tid < 8){
    int tt = blockIdx.x*8 + tid;
    int i1=0; double m1=lg[tid][0];
#pragma unroll
    for(int k=1;k<NE;k++) if(lg[tid][k]>m1){ m1=lg[tid][k]; i1=k; }
    int i2=-1; double m2=-1e300;
#pragma unroll
    for(int k=0;k<NE;k++) if(k!=i1 && lg[tid][k]>m2){ m2=lg[tid][k]; i2=k; }
    float e2 = __expf((float)(m2-m1));
    float w0 = 1.f/(1.f+e2);
    idxs[2*tt]=i1; idxs[2*tt+1]=i2;
    wt[2*tt]=w0;   wt[2*tt+1]=e2*w0;
    atomicAdd(&cnt[i1],1); atomicAdd(&cnt[i2],1);
  }

  // bf16 copy of the block's 8 x-rows
  const f32x4* xs = reinterpret_cast<const f32x4*>(x) + (size_t)blockIdx.x*2048;
  __bf16* xo = xb + (size_t)blockIdx.x*8192;
#pragma unroll
  for(int k=0;k<4;k++){
    int c = k*256 + tid;
    cvt_st8(xo + (size_t)c*8, xs[2*c], xs[2*c+1]);
  }

  // zero this block's 8 y rows, ready for ffn2 atomics
  f32x4* yz = reinterpret_cast<f32x4*>(y) + (size_t)blockIdx.x*2048;
#pragma unroll
  for(int k=0;k<8;k++)
    yz[k*256 + tid] = f32x4{0.f,0.f,0.f,0.f};
}

__global__ void k_prep(const int* __restrict__ cnt, int* __restrict__ off,
                       int* __restrict__ mtp, int* __restrict__ cursor)
{
  if(threadIdx.x==0){
    int o=0, m=0; off[0]=0; mtp[0]=0;
    for(int e=0;e<NE;e++){
      cursor[e]=o; o += cnt[e]; off[e+1]=o;
      m += (cnt[e]+BM-1)/BM;  mtp[e+1]=m;
    }
  }
}

__global__ __launch_bounds__(256) void k_scatter(const int* __restrict__ idxs,
    int* __restrict__ cursor, int* __restrict__ order)
{
  int t = blockIdx.x*blockDim.x + threadIdx.x;
#pragma unroll
  for(int k=0;k<2;k++){
    int s = 2*t+k;
    int e = idxs[s];
    int p = atomicAdd(&cursor[e],1);
    order[p]=s;
  }
}

// ======== FFN1 (R12-proven): 128x128x2, BK=32 — split in nt-halves ========
#define NT_H 11
__global__ __launch_bounds__(512) void k_ffn1(
    const __bf16* __restrict__ xb, const __bf16* __restrict__ w1b,
    const __bf16* __restrict__ w3b, const int* __restrict__ off,
    const int* __restrict__ mtp, const int* __restrict__ order,
    __bf16* __restrict__ h, int nt_off)
{
  __shared__ __align__(16) __bf16 lA [2][BM*BK];
  __shared__ __align__(16) __bf16 lB1[2][BM*BK];
  __shared__ __align__(16) __bf16 lB3[2][BM*BK];

  int wg = xcd_map(blockIdx.x, MAXMT*NT_H);
  int mt = wg / NT_H, nt = nt_off + wg % NT_H;
  if (mt >= mtp[NE]) return;
  int e = 0;
  while (mt >= mtp[e+1]) e++;
  int row0    = off[e] + (mt - mtp[e])*BM;
  int row_end = off[e+1];
  int n0      = nt*128;

  int tid = threadIdx.x, lane = tid&63;
  int srow = tid>>2;
  int scol = ((tid&3) ^ ((srow>>1)&3))<<3;   // pre-swizzled source granule
  int arow = min(row0 + srow, row_end-1);
  int tok  = order[arow] >> 1;
  const __bf16* gA  = xb  + (size_t)tok*DIM + scol;
  const __bf16* gB1 = w1b + (size_t)e*HID*DIM + (size_t)(n0+srow)*DIM + scol;
  const __bf16* gB3 = w3b + (size_t)e*HID*DIM + (size_t)(n0+srow)*DIM + scol;
  int ldso = (tid>>6)<<9;                // wave * 512 elements (1KB)

  int wm = (tid>>6)>>2, wn = (tid>>6)&3; // 2x4 wave grid, wave tile 64x32 (x2 tensors)
  int fr = lane & 15, gq = lane>>4;

  f32x4 acc1[4][2], acc3[4][2];
#pragma unroll
  for(int m=0;m<4;m++)
#pragma unroll
    for(int n=0;n<2;n++){ acc1[m][n]=f32x4{0.f,0.f,0.f,0.f}; acc3[m][n]=f32x4{0.f,0.f,0.f,0.f}; }

  gld_lds16(gA,  &lA [0][ldso]);
  gld_lds16(gB1, &lB1[0][ldso]);
  gld_lds16(gB3, &lB3[0][ldso]);
  __syncthreads();

  const int NK = DIM/BK;                 // 32
  int buf=0;
  for(int kt=0; kt<NK; kt++){
    if(kt+1<NK){
      gld_lds16(gA  + (kt+1)*BK, &lA [buf^1][ldso]);
      gld_lds16(gB1 + (kt+1)*BK, &lB1[buf^1][ldso]);
      gld_lds16(gB3 + (kt+1)*BK, &lB3[buf^1][ldso]);
    }
    bf16x8 av[4], bv[2], cv[2];
#pragma unroll
    for(int m=0;m<4;m++) av[m]=*reinterpret_cast<const bf16x8*>(&lA[buf][SWZ(wm*64+m*16+fr, gq)]);
#pragma unroll
    for(int n=0;n<2;n++){
      bv[n]=*reinterpret_cast<const bf16x8*>(&lB1[buf][SWZ(wn*32+n*16+fr, gq)]);
      cv[n]=*reinterpret_cast<const bf16x8*>(&lB3[buf][SWZ(wn*32+n*16+fr, gq)]);
    }
#pragma unroll
    for(int m=0;m<4;m++)
#pragma unroll
      for(int n=0;n<2;n++){
        acc1[m][n]=MFMA(av[m],bv[n],acc1[m][n]);
        acc3[m][n]=MFMA(av[m],cv[n],acc3[m][n]);
      }
    __syncthreads();
    buf^=1;
  }

#pragma unroll
  for(int m=0;m<4;m++){
    int rbase = row0 + wm*64 + m*16 + (gq<<2);
#pragma unroll
    for(int r=0;r<4;r++){
      if(rbase+r < row_end){
        __bf16* hp = h + (size_t)(rbase+r)*HID + n0 + wn*32 + fr;
#pragma unroll
        for(int n=0;n<2;n++){
          float u = acc1[m][n][r], v = acc3[m][n][r];
          hp[n*16] = (__bf16)( (u/(1.f+__expf(-u))) * v );
        }
      }
    }
  }
}

// ======== FFN2 (R12-proven): 128x128, 256 thr, dbuf, BK=32 — split in nt-halves,
// fused weighted atomic epilogue into y ========
__global__ __launch_bounds__(256) void k_ffn2(
    const __bf16* __restrict__ h, const __bf16* __restrict__ w2b,
    const int* __restrict__ off, const int* __restrict__ mtp,
    const int* __restrict__ order, const float* __restrict__ wt,
    float* __restrict__ y, int nt_off)
{
  __shared__ __align__(16) __bf16 lA[2][128*BK];    // 8 KB per buf
  __shared__ __align__(16) __bf16 lB[2][128*BK];

  const int NTH = 4;                     // half of DIM/128
  int wg = xcd_map(blockIdx.x, MAXMT*NTH);
  int mt = wg / NTH, nt = nt_off + wg % NTH;
  if (mt >= mtp[NE]) return;
  int e = 0;
  while (mt >= mtp[e+1]) e++;
  int row0    = off[e] + (mt - mtp[e])*BM;
  int row_end = off[e+1];
  int n0      = nt*128;

  int tid = threadIdx.x, lane = tid&63, wave = tid>>6;  // 4 waves
  int srow = tid>>2;                     // 0..63
  int scol = ((tid&3) ^ ((srow>>1)&3))<<3;   // same XOR phase valid for srow+64 (64%8==0)
  int hr0 = min(row0 + srow,      NSLOT-1);
  int hr1 = min(row0 + srow + 64, NSLOT-1);
  const __bf16* gA0 = h   + (size_t)hr0*HID + scol;
  const __bf16* gA1 = h   + (size_t)hr1*HID + scol;
  const __bf16* gB0 = w2b + (size_t)e*DIM*HID + (size_t)(n0+srow)*HID + scol;
  const __bf16* gB1 = w2b + (size_t)e*DIM*HID + (size_t)(n0+srow+64)*HID + scol;
  int ldso = wave<<9;                    // wave * 512 elements (1KB)

  int wm = wave>>1, wn = wave&1;         // 2x2 wave grid; wave tile 64(M)x64(N)
  int fr = lane&15, gq = lane>>4;

  f32x4 acc[4][4];
#pragma unroll
  for(int m=0;m<4;m++)
#pragma unroll
    for(int n=0;n<4;n++) acc[m][n]=f32x4{0.f,0.f,0.f,0.f};

  gld_lds16(gA0, &lA[0][ldso]);
  gld_lds16(gA1, &lA[0][2048+ldso]);
  gld_lds16(gB0, &lB[0][ldso]);
  gld_lds16(gB1, &lB[0][2048+ldso]);
  __syncthreads();

  const int NK = HID/BK;                 // 88
  int buf=0;
  for(int kt=0; kt<NK; kt++){
    if(kt+1<NK){
      gld_lds16(gA0 + (kt+1)*BK, &lA[buf^1][ldso]);
      gld_lds16(gA1 + (kt+1)*BK, &lA[buf^1][2048+ldso]);
      gld_lds16(gB0 + (kt+1)*BK, &lB[buf^1][ldso]);
      gld_lds16(gB1 + (kt+1)*BK, &lB[buf^1][2048+ldso]);
    }
    bf16x8 av[4], bv[4];
#pragma unroll
    for(int m=0;m<4;m++) av[m]=*reinterpret_cast<const bf16x8*>(&lA[buf][SWZ(wm*64+m*16+fr, gq)]);
#pragma unroll
    for(int n=0;n<4;n++) bv[n]=*reinterpret_cast<const bf16x8*>(&lB[buf][SWZ(wn*64+n*16+fr, gq)]);
#pragma unroll
    for(int m=0;m<4;m++)
#pragma unroll
      for(int n=0;n<4;n++)
        acc[m][n]=MFMA(av[m],bv[n],acc[m][n]);
    __syncthreads();
    buf^=1;
  }

  // epilogue: weighted atomic combine into y (2 commutative addends/element)
#pragma unroll
  for(int m=0;m<4;m++){
    int rbase = row0 + wm*64 + m*16 + (gq<<2);
#pragma unroll
    for(int r=0;r<4;r++){
      int p = rbase + r;
      if(p < row_end){
        int s = order[p];
        float wv = wt[s];
        float* yp = y + (size_t)(s>>1)*DIM + n0 + wn*64 + fr;
#pragma unroll
        for(int n=0;n<4;n++) atomicAdd(&yp[n*16], wv*acc[m][n][r]);
      }
    }
  }
}

// ---------------- launch ----------------
extern "C" void kernel_launch(void* const* d_in, const int* in_sizes, int n_in,
                              void* d_out, int out_size, void* d_ws, size_t ws_size,
                              hipStream_t stream)
{
  const float* x  = (const float*)d_in[0];
  const float* gw = (const float*)d_in[1];
  const float* w1 = (const float*)d_in[2];
  const float* w3 = (const float*)d_in[3];
  const float* w2 = (const float*)d_in[4];
  float* y = (float*)d_out;
  char* ws = (char*)d_ws;

  int*   cnt    = (int*)(ws + 0);
  int*   off    = (int*)(ws + 64);
  int*   mtp    = (int*)(ws + 128);
  int*   cursor = (int*)(ws + 256);
  int*   idxs   = (int*)(ws + 320);
  float* wt     = (float*)(ws + 320 + 65536);
  int*   order  = (int*)(ws + 320 + 2*65536);
  __bf16* h     = (__bf16*)(ws + 262464);
  __bf16* xb    = (__bf16*)(ws + 262464 + 92274688ull);
  __bf16* w1b   = (__bf16*)(ws + 262464 + 92274688ull + 16777216ull);
  __bf16* w3b   = (__bf16*)(ws + 262464 + 92274688ull + 16777216ull + 46137344ull);
  __bf16* w2b   = (__bf16*)(ws + 262464 + 92274688ull + 16777216ull + 2*46137344ull);

  k_cvt3   <<<3*CVTPB, 256, 0, stream>>>(w1, w3, w2, w1b, w3b, w2b, cnt);
  k_gate   <<<NTOK/8, 256, 0, stream>>>(x, gw, idxs, wt, cnt, xb, y);
  k_prep   <<<1, 64, 0, stream>>>(cnt, off, mtp, cursor);
  k_scatter<<<NTOK/256, 256, 0, stream>>>(idxs, cursor, order);
  k_ffn1   <<<MAXMT*NT_H, 512, 0, stream>>>(xb, w1b, w3b, off, mtp, order, h, 0);
  k_ffn1   <<<MAXMT*NT_H, 512, 0, stream>>>(xb, w1b, w3b, off, mtp, order, h, NT_H);
  k_ffn2   <<<MAXMT*4, 256, 0, stream>>>(h, w2b, off, mtp, order, wt, y, 0);
  k_ffn2   <<<MAXMT*4, 256, 0, stream>>>(h, w2b, off, mtp, order, wt, y, 4);
}

// Round 15
// 658.732 us; speedup vs baseline: 1.2252x; 1.0292x over previous
//
#include <hip/hip_runtime.h>
#include <hip/hip_bf16.h>

#define NTOK 8192
#define DIM 1024
#define HID 2816
#define NE 8
#define NSLOT (NTOK*2)
#define BM 128
#define BK 32
#define MAXMT (NSLOT/BM + NE)   // 136 worst-case M-tiles @ BM=128

typedef float f32x4 __attribute__((ext_vector_type(4)));
typedef __bf16 bf16x8 __attribute__((ext_vector_type(8)));
typedef __bf16 bf16x4 __attribute__((ext_vector_type(4)));

#define MFMA(a,b,c) __builtin_amdgcn_mfma_f32_16x16x32_bf16(a,b,c,0,0,0)
// element index in a linear [rows][32] bf16 tile, XOR bank swizzle (R2-proven: 0 conflicts)
#define SWZ(r,g) (((r)<<5) + ((((g) ^ (((r)>>1)&3)))<<3))

__device__ __forceinline__ void cvt_st8(__bf16* d, f32x4 a, f32x4 b){
  bf16x8 v;
  v[0]=(__bf16)a.x; v[1]=(__bf16)a.y; v[2]=(__bf16)a.z; v[3]=(__bf16)a.w;
  v[4]=(__bf16)b.x; v[5]=(__bf16)b.y; v[6]=(__bf16)b.z; v[7]=(__bf16)b.w;
  *reinterpret_cast<bf16x8*>(d) = v;
}
__device__ __forceinline__ void gld_lds16(const void* g, void* l){
  __builtin_amdgcn_global_load_lds(
    (const __attribute__((address_space(1))) void*)g,
    (__attribute__((address_space(3))) void*)l, 16, 0, 0);
}
__device__ __forceinline__ int xcd_map(int orig, int nwg){
  int q = nwg>>3, rr = nwg&7, x = orig&7, o = orig>>3;
  return (x<rr ? x*(q+1) : rr*(q+1)+(x-rr)*q) + o;
}

// ---------------- fused fp32->bf16 conversion (fat threads, NT loads) ----------------
#define CVTPB (NE*HID*DIM/16/256)   // 5632 blocks per tensor
__global__ __launch_bounds__(256) void k_cvt3(
    const float* __restrict__ s1, const float* __restrict__ s3,
    const float* __restrict__ s2, __bf16* __restrict__ d1,
    __bf16* __restrict__ d3, __bf16* __restrict__ d2, int* __restrict__ cnt)
{
  if(blockIdx.x==0 && threadIdx.x < NE) cnt[threadIdx.x] = 0;
  int seg = blockIdx.x / CVTPB;
  size_t i = (size_t)(blockIdx.x % CVTPB)*256 + threadIdx.x;   // unit of 16 f32
  const float* src = (seg==0) ? s1 : (seg==1) ? s3 : s2;
  __bf16*      dst = (seg==0) ? d1 : (seg==1) ? d3 : d2;
  const f32x4* s = reinterpret_cast<const f32x4*>(src) + i*4;
  f32x4 a = __builtin_nontemporal_load(s);      // fp32 source is read-once:
  f32x4 b = __builtin_nontemporal_load(s+1);    // don't pollute L2/L3
  f32x4 c = __builtin_nontemporal_load(s+2);
  f32x4 d = __builtin_nontemporal_load(s+3);
  cvt_st8(dst + i*16,     a, b);
  cvt_st8(dst + i*16 + 8, c, d);
}

// ---- gating: lane-parallel f64 dots (R7-proven); no y zeroing (combine overwrites) ----
__global__ __launch_bounds__(256) void k_gate(const float* __restrict__ x,
    const float* __restrict__ gw, int* __restrict__ idxs,
    float* __restrict__ wt, int* __restrict__ cnt, __bf16* __restrict__ xb)
{
  __shared__ double part[8][8][4];
  __shared__ double lg[8][8];

  int tid = threadIdx.x;
  int tl = tid>>5, e = (tid>>2)&7, q = tid&3;
  int t  = blockIdx.x*8 + tl;

  const f32x4* x4 = reinterpret_cast<const f32x4*>(x)  + (size_t)t*256 + q*64;
  const f32x4* g4 = reinterpret_cast<const f32x4*>(gw) + e*256 + q*64;

  double s0 = 0.0, s1 = 0.0;
#pragma unroll 4
  for(int j=0;j<64;j+=2){
    f32x4 a0 = x4[j],   b0 = g4[j];
    f32x4 a1 = x4[j+1], b1 = g4[j+1];
    s0 += (double)a0.x*b0.x + (double)a0.y*b0.y
        + (double)a0.z*b0.z + (double)a0.w*b0.w;
    s1 += (double)a1.x*b1.x + (double)a1.y*b1.y
        + (double)a1.z*b1.z + (double)a1.w*b1.w;
  }
  part[tl][e][q] = s0 + s1;
  __syncthreads();
  if(q==0)
    lg[tl][e] = part[tl][e][0] + part[tl][e][1] + part[tl][e][2] + part[tl][e][3];
  __syncthreads();

  if(tid < 8){
    int tt = blockIdx.x*8 + tid;
    int i1=0; double m1=lg[tid][0];
#pragma unroll
    for(int k=1;k<NE;k++) if(lg[tid][k]>m1){ m1=lg[tid][k]; i1=k; }
    int i2=-1; double m2=-1e300;
#pragma unroll
    for(int k=0;k<NE;k++) if(k!=i1 && lg[tid][k]>m2){ m2=lg[tid][k]; i2=k; }
    float e2 = __expf((float)(m2-m1));
    float w0 = 1.f/(1.f+e2);
    idxs[2*tt]=i1; idxs[2*tt+1]=i2;
    wt[2*tt]=w0;   wt[2*tt+1]=e2*w0;
    atomicAdd(&cnt[i1],1); atomicAdd(&cnt[i2],1);
  }

  // bf16 copy of the block's 8 x-rows
  const f32x4* xs = reinterpret_cast<const f32x4*>(x) + (size_t)blockIdx.x*2048;
  __bf16* xo = xb + (size_t)blockIdx.x*8192;
#pragma unroll
  for(int k=0;k<4;k++){
    int c = k*256 + tid;
    cvt_st8(xo + (size_t)c*8, xs[2*c], xs[2*c+1]);
  }
}

__global__ void k_prep(const int* __restrict__ cnt, int* __restrict__ off,
                       int* __restrict__ mtp, int* __restrict__ cursor)
{
  if(threadIdx.x==0){
    int o=0, m=0; off[0]=0; mtp[0]=0;
    for(int e=0;e<NE;e++){
      cursor[e]=o; o += cnt[e]; off[e+1]=o;
      m += (cnt[e]+BM-1)/BM;  mtp[e+1]=m;
    }
  }
}

__global__ __launch_bounds__(256) void k_scatter(const int* __restrict__ idxs,
    int* __restrict__ cursor, int* __restrict__ order, int* __restrict__ inv)
{
  int t = blockIdx.x*blockDim.x + threadIdx.x;
#pragma unroll
  for(int k=0;k<2;k++){
    int s = 2*t+k;
    int e = idxs[s];
    int p = atomicAdd(&cursor[e],1);
    order[p]=s; inv[s]=p;
  }
}

// ======== FFN1 (R12-proven, merged): h = silu(x@w1^T)*(x@w3^T), 128x128x2, BK=32 ========
__global__ __launch_bounds__(512) void k_ffn1(
    const __bf16* __restrict__ xb, const __bf16* __restrict__ w1b,
    const __bf16* __restrict__ w3b, const int* __restrict__ off,
    const int* __restrict__ mtp, const int* __restrict__ order,
    __bf16* __restrict__ h)
{
  __shared__ __align__(16) __bf16 lA [2][BM*BK];
  __shared__ __align__(16) __bf16 lB1[2][BM*BK];
  __shared__ __align__(16) __bf16 lB3[2][BM*BK];

  const int NT = HID/128;                // 22
  int wg = xcd_map(blockIdx.x, MAXMT*NT);
  int mt = wg / NT, nt = wg % NT;
  if (mt >= mtp[NE]) return;
  int e = 0;
  while (mt >= mtp[e+1]) e++;
  int row0    = off[e] + (mt - mtp[e])*BM;
  int row_end = off[e+1];
  int n0      = nt*128;

  int tid = threadIdx.x, lane = tid&63;
  int srow = tid>>2;
  int scol = ((tid&3) ^ ((srow>>1)&3))<<3;   // pre-swizzled source granule
  int arow = min(row0 + srow, row_end-1);
  int tok  = order[arow] >> 1;
  const __bf16* gA  = xb  + (size_t)tok*DIM + scol;
  const __bf16* gB1 = w1b + (size_t)e*HID*DIM + (size_t)(n0+srow)*DIM + scol;
  const __bf16* gB3 = w3b + (size_t)e*HID*DIM + (size_t)(n0+srow)*DIM + scol;
  int ldso = (tid>>6)<<9;                // wave * 512 elements (1KB)

  int wm = (tid>>6)>>2, wn = (tid>>6)&3; // 2x4 wave grid, wave tile 64x32 (x2 tensors)
  int fr = lane & 15, gq = lane>>4;

  f32x4 acc1[4][2], acc3[4][2];
#pragma unroll
  for(int m=0;m<4;m++)
#pragma unroll
    for(int n=0;n<2;n++){ acc1[m][n]=f32x4{0.f,0.f,0.f,0.f}; acc3[m][n]=f32x4{0.f,0.f,0.f,0.f}; }

  gld_lds16(gA,  &lA [0][ldso]);
  gld_lds16(gB1, &lB1[0][ldso]);
  gld_lds16(gB3, &lB3[0][ldso]);
  __syncthreads();

  const int NK = DIM/BK;                 // 32
  int buf=0;
  for(int kt=0; kt<NK; kt++){
    if(kt+1<NK){
      gld_lds16(gA  + (kt+1)*BK, &lA [buf^1][ldso]);
      gld_lds16(gB1 + (kt+1)*BK, &lB1[buf^1][ldso]);
      gld_lds16(gB3 + (kt+1)*BK, &lB3[buf^1][ldso]);
    }
    bf16x8 av[4], bv[2], cv[2];
#pragma unroll
    for(int m=0;m<4;m++) av[m]=*reinterpret_cast<const bf16x8*>(&lA[buf][SWZ(wm*64+m*16+fr, gq)]);
#pragma unroll
    for(int n=0;n<2;n++){
      bv[n]=*reinterpret_cast<const bf16x8*>(&lB1[buf][SWZ(wn*32+n*16+fr, gq)]);
      cv[n]=*reinterpret_cast<const bf16x8*>(&lB3[buf][SWZ(wn*32+n*16+fr, gq)]);
    }
#pragma unroll
    for(int m=0;m<4;m++)
#pragma unroll
      for(int n=0;n<2;n++){
        acc1[m][n]=MFMA(av[m],bv[n],acc1[m][n]);
        acc3[m][n]=MFMA(av[m],cv[n],acc3[m][n]);
      }
    __syncthreads();
    buf^=1;
  }

#pragma unroll
  for(int m=0;m<4;m++){
    int rbase = row0 + wm*64 + m*16 + (gq<<2);
#pragma unroll
    for(int r=0;r<4;r++){
      if(rbase+r < row_end){
        __bf16* hp = h + (size_t)(rbase+r)*HID + n0 + wn*32 + fr;
#pragma unroll
        for(int n=0;n<2;n++){
          float u = acc1[m][n][r], v = acc3[m][n][r];
          hp[n*16] = (__bf16)( (u/(1.f+__expf(-u))) * v );
        }
      }
    }
  }
}

// ======== FFN2 (R8-proven, merged): ys = h @ w2^T, 128x128, 256 thr, dbuf ========
__global__ __launch_bounds__(256) void k_ffn2(
    const __bf16* __restrict__ h, const __bf16* __restrict__ w2b,
    const int* __restrict__ off, const int* __restrict__ mtp,
    __bf16* __restrict__ ys)
{
  __shared__ __align__(16) __bf16 lA[2][128*BK];    // 8 KB per buf
  __shared__ __align__(16) __bf16 lB[2][128*BK];

  const int NT = DIM/128;                // 8
  int wg = xcd_map(blockIdx.x, MAXMT*NT);
  int mt = wg / NT, nt = wg % NT;
  if (mt >= mtp[NE]) return;
  int e = 0;
  while (mt >= mtp[e+1]) e++;
  int row0    = off[e] + (mt - mtp[e])*BM;
  int row_end = off[e+1];
  int n0      = nt*128;

  int tid = threadIdx.x, lane = tid&63, wave = tid>>6;  // 4 waves
  int srow = tid>>2;                     // 0..63
  int scol = ((tid&3) ^ ((srow>>1)&3))<<3;   // same XOR phase valid for srow+64 (64%8==0)
  int hr0 = min(row0 + srow,      NSLOT-1);
  int hr1 = min(row0 + srow + 64, NSLOT-1);
  const __bf16* gA0 = h   + (size_t)hr0*HID + scol;
  const __bf16* gA1 = h   + (size_t)hr1*HID + scol;
  const __bf16* gB0 = w2b + (size_t)e*DIM*HID + (size_t)(n0+srow)*HID + scol;
  const __bf16* gB1 = w2b + (size_t)e*DIM*HID + (size_t)(n0+srow+64)*HID + scol;
  int ldso = wave<<9;                    // wave * 512 elements (1KB)

  int wm = wave>>1, wn = wave&1;         // 2x2 wave grid; wave tile 64(M)x64(N)
  int fr = lane&15, gq = lane>>4;

  f32x4 acc[4][4];
#pragma unroll
  for(int m=0;m<4;m++)
#pragma unroll
    for(int n=0;n<4;n++) acc[m][n]=f32x4{0.f,0.f,0.f,0.f};

  gld_lds16(gA0, &lA[0][ldso]);
  gld_lds16(gA1, &lA[0][2048+ldso]);
  gld_lds16(gB0, &lB[0][ldso]);
  gld_lds16(gB1, &lB[0][2048+ldso]);
  __syncthreads();

  const int NK = HID/BK;                 // 88
  int buf=0;
  for(int kt=0; kt<NK; kt++){
    if(kt+1<NK){
      gld_lds16(gA0 + (kt+1)*BK, &lA[buf^1][ldso]);
      gld_lds16(gA1 + (kt+1)*BK, &lA[buf^1][2048+ldso]);
      gld_lds16(gB0 + (kt+1)*BK, &lB[buf^1][ldso]);
      gld_lds16(gB1 + (kt+1)*BK, &lB[buf^1][2048+ldso]);
    }
    bf16x8 av[4], bv[4];
#pragma unroll
    for(int m=0;m<4;m++) av[m]=*reinterpret_cast<const bf16x8*>(&lA[buf][SWZ(wm*64+m*16+fr, gq)]);
#pragma unroll
    for(int n=0;n<4;n++) bv[n]=*reinterpret_cast<const bf16x8*>(&lB[buf][SWZ(wn*64+n*16+fr, gq)]);
#pragma unroll
    for(int m=0;m<4;m++)
#pragma unroll
      for(int n=0;n<4;n++)
        acc[m][n]=MFMA(av[m],bv[n],acc[m][n]);
    __syncthreads();
    buf^=1;
  }

  // epilogue: per-slot bf16 ys (no atomics)
#pragma unroll
  for(int m=0;m<4;m++){
    int rbase = row0 + wm*64 + m*16 + (gq<<2);
#pragma unroll
    for(int r=0;r<4;r++){
      if(rbase+r < row_end){
        __bf16* yp = ys + (size_t)(rbase+r)*DIM + n0 + wn*64 + fr;
#pragma unroll
        for(int n=0;n<4;n++) yp[n*16] = (__bf16)acc[m][n][r];
      }
    }
  }
}

// ---------------- weighted combine (fully overwrites y) ----------------
__global__ __launch_bounds__(256) void k_combine(
    const __bf16* __restrict__ ys, const int* __restrict__ inv,
    const float* __restrict__ wt, float* __restrict__ y)
{
  int t  = blockIdx.x;
  int p0 = inv[2*t], p1 = inv[2*t+1];
  float w0 = wt[2*t], w1v = wt[2*t+1];
  int d = threadIdx.x*4;
  const __bf16* r0 = ys + (size_t)p0*DIM + d;
  const __bf16* r1 = ys + (size_t)p1*DIM + d;
  f32x4 o;
#pragma unroll
  for(int j=0;j<4;j++) o[j] = w0*(float)r0[j] + w1v*(float)r1[j];
  *reinterpret_cast<f32x4*>(y + (size_t)t*DIM + d) = o;
}

// ---------------- launch ----------------
extern "C" void kernel_launch(void* const* d_in, const int* in_sizes, int n_in,
                              void* d_out, int out_size, void* d_ws, size_t ws_size,
                              hipStream_t stream)
{
  const float* x  = (const float*)d_in[0];
  const float* gw = (const float*)d_in[1];
  const float* w1 = (const float*)d_in[2];
  const float* w3 = (const float*)d_in[3];
  const float* w2 = (const float*)d_in[4];
  float* y = (float*)d_out;
  char* ws = (char*)d_ws;

  int*   cnt    = (int*)(ws + 0);
  int*   off    = (int*)(ws + 64);
  int*   mtp    = (int*)(ws + 128);
  int*   cursor = (int*)(ws + 256);
  int*   idxs   = (int*)(ws + 320);
  float* wt     = (float*)(ws + 320 + 65536);
  int*   order  = (int*)(ws + 320 + 2*65536);
  int*   inv    = (int*)(ws + 320 + 3*65536);
  __bf16* h     = (__bf16*)(ws + 262464);
  __bf16* xb    = (__bf16*)(ws + 262464 + 92274688ull);
  __bf16* w1b   = (__bf16*)(ws + 262464 + 92274688ull + 16777216ull);
  __bf16* w3b   = (__bf16*)(ws + 262464 + 92274688ull + 16777216ull + 46137344ull);
  __bf16* w2b   = (__bf16*)(ws + 262464 + 92274688ull + 16777216ull + 2*46137344ull);
  __bf16* ysb   = w1b;   // dead after k_ffn1 -> reuse (33.5MB <= 46MB)

  k_cvt3   <<<3*CVTPB, 256, 0, stream>>>(w1, w3, w2, w1b, w3b, w2b, cnt);
  k_gate   <<<NTOK/8, 256, 0, stream>>>(x, gw, idxs, wt, cnt, xb);
  k_prep   <<<1, 64, 0, stream>>>(cnt, off, mtp, cursor);
  k_scatter<<<NTOK/256, 256, 0, stream>>>(idxs, cursor, order, inv);
  k_ffn1   <<<MAXMT*(HID/128), 512, 0, stream>>>(xb, w1b, w3b, off, mtp, order, h);
  k_ffn2   <<<MAXMT*(DIM/128), 256, 0, stream>>>(h, w2b, off, mtp, ysb);
  k_combine<<<NTOK, 256, 0, stream>>>(ysb, inv, wt, y);
}

// Round 16
// 615.972 us; speedup vs baseline: 1.3102x; 1.0694x over previous
//
#include <hip/hip_runtime.h>
#include <hip/hip_bf16.h>

#define NTOK 8192
#define DIM 1024
#define HID 2816
#define NE 8
#define NSLOT (NTOK*2)
#define BM 128
#define BK 32
#define MAXMT (NSLOT/BM + NE)   // 136 worst-case M-tiles @ BM=128

typedef float f32x4 __attribute__((ext_vector_type(4)));
typedef __bf16 bf16x8 __attribute__((ext_vector_type(8)));
typedef __bf16 bf16x4 __attribute__((ext_vector_type(4)));

#define MFMA(a,b,c) __builtin_amdgcn_mfma_f32_16x16x32_bf16(a,b,c,0,0,0)
// element index in a linear [rows][32] bf16 tile, XOR bank swizzle (R2-proven: 0 conflicts)
#define SWZ(r,g) (((r)<<5) + ((((g) ^ (((r)>>1)&3)))<<3))

__device__ __forceinline__ void cvt_st8(__bf16* d, f32x4 a, f32x4 b){
  bf16x8 v;
  v[0]=(__bf16)a.x; v[1]=(__bf16)a.y; v[2]=(__bf16)a.z; v[3]=(__bf16)a.w;
  v[4]=(__bf16)b.x; v[5]=(__bf16)b.y; v[6]=(__bf16)b.z; v[7]=(__bf16)b.w;
  *reinterpret_cast<bf16x8*>(d) = v;
}
__device__ __forceinline__ void gld_lds16(const void* g, void* l){
  __builtin_amdgcn_global_load_lds(
    (const __attribute__((address_space(1))) void*)g,
    (__attribute__((address_space(3))) void*)l, 16, 0, 0);
}
__device__ __forceinline__ int xcd_map(int orig, int nwg){
  int q = nwg>>3, rr = nwg&7, x = orig&7, o = orig>>3;
  return (x<rr ? x*(q+1) : rr*(q+1)+(x-rr)*q) + o;
}

// ======== fused gate + weight-conversion (grid-section kernel) ========
// blocks [0,GATEB): gating (latency-bound, scheduled first);
// blocks [GATEB, GATEB+3*CVTPB): fp32->bf16 weight conversion (BW-bound, fills in).
#define GATEB (NTOK/8)              // 1024
#define CVTPB (NE*HID*DIM/16/256)   // 5632 blocks per tensor
__global__ __launch_bounds__(256) void k_cvtgate(
    const float* __restrict__ x,  const float* __restrict__ gw,
    const float* __restrict__ s1, const float* __restrict__ s3,
    const float* __restrict__ s2, __bf16* __restrict__ d1,
    __bf16* __restrict__ d3, __bf16* __restrict__ d2,
    int* __restrict__ idxs, float* __restrict__ wt, __bf16* __restrict__ xb)
{
  int tid = threadIdx.x;
  if(blockIdx.x >= GATEB){
    // ---- weight conversion section (R14/R15-proven fat threads + NT loads) ----
    int cb  = blockIdx.x - GATEB;
    int seg = cb / CVTPB;
    size_t i = (size_t)(cb % CVTPB)*256 + tid;   // unit of 16 f32
    const float* src = (seg==0) ? s1 : (seg==1) ? s3 : s2;
    __bf16*      dst = (seg==0) ? d1 : (seg==1) ? d3 : d2;
    const f32x4* s = reinterpret_cast<const f32x4*>(src) + i*4;
    f32x4 a = __builtin_nontemporal_load(s);     // fp32 source is read-once
    f32x4 b = __builtin_nontemporal_load(s+1);
    f32x4 c = __builtin_nontemporal_load(s+2);
    f32x4 d = __builtin_nontemporal_load(s+3);
    cvt_st8(dst + i*16,     a, b);
    cvt_st8(dst + i*16 + 8, c, d);
    return;
  }

  // ---- gating section (R7-proven lane-parallel f64 dots; no cnt atomics) ----
  __shared__ double part[8][8][4];
  __shared__ double lg[8][8];

  int tl = tid>>5, e = (tid>>2)&7, q = tid&3;
  int t  = blockIdx.x*8 + tl;

  const f32x4* x4 = reinterpret_cast<const f32x4*>(x)  + (size_t)t*256 + q*64;
  const f32x4* g4 = reinterpret_cast<const f32x4*>(gw) + e*256 + q*64;

  double s0 = 0.0, s1d = 0.0;
#pragma unroll 4
  for(int j=0;j<64;j+=2){
    f32x4 a0 = x4[j],   b0 = g4[j];
    f32x4 a1 = x4[j+1], b1 = g4[j+1];
    s0  += (double)a0.x*b0.x + (double)a0.y*b0.y
         + (double)a0.z*b0.z + (double)a0.w*b0.w;
    s1d += (double)a1.x*b1.x + (double)a1.y*b1.y
         + (double)a1.z*b1.z + (double)a1.w*b1.w;
  }
  part[tl][e][q] = s0 + s1d;
  __syncthreads();
  if(q==0)
    lg[tl][e] = part[tl][e][0] + part[tl][e][1] + part[tl][e][2] + part[tl][e][3];
  __syncthreads();

  if(tid < 8){
    int tt = blockIdx.x*8 + tid;
    int i1=0; double m1=lg[tid][0];
#pragma unroll
    for(int k=1;k<NE;k++) if(lg[tid][k]>m1){ m1=lg[tid][k]; i1=k; }
    int i2=-1; double m2=-1e300;
#pragma unroll
    for(int k=0;k<NE;k++) if(k!=i1 && lg[tid][k]>m2){ m2=lg[tid][k]; i2=k; }
    float e2 = __expf((float)(m2-m1));
    float w0 = 1.f/(1.f+e2);
    idxs[2*tt]=i1; idxs[2*tt+1]=i2;
    wt[2*tt]=w0;   wt[2*tt+1]=e2*w0;
  }

  // bf16 copy of the block's 8 x-rows
  const f32x4* xs = reinterpret_cast<const f32x4*>(x) + (size_t)blockIdx.x*2048;
  __bf16* xo = xb + (size_t)blockIdx.x*8192;
#pragma unroll
  for(int k=0;k<4;k++){
    int c = k*256 + tid;
    cvt_st8(xo + (size_t)c*8, xs[2*c], xs[2*c+1]);
  }
}

// ---- prep: histogram idxs -> cnt, then serial prefix (replaces gate atomics) ----
__global__ __launch_bounds__(256) void k_prep(const int* __restrict__ idxs,
    int* __restrict__ off, int* __restrict__ mtp, int* __restrict__ cursor)
{
  __shared__ int hist[NE];
  int tid = threadIdx.x;
  if(tid < NE) hist[tid] = 0;
  __syncthreads();
  int local[NE] = {0,0,0,0,0,0,0,0};
  for(int k=0;k<NSLOT/256;k++){
    int e = idxs[tid*(NSLOT/256) + k];
    local[e]++;
  }
#pragma unroll
  for(int e=0;e<NE;e++) if(local[e]) atomicAdd(&hist[e], local[e]);
  __syncthreads();
  if(tid==0){
    int o=0, m=0; off[0]=0; mtp[0]=0;
    for(int e=0;e<NE;e++){
      cursor[e]=o; o += hist[e]; off[e+1]=o;
      m += (hist[e]+BM-1)/BM;  mtp[e+1]=m;
    }
  }
}

__global__ __launch_bounds__(256) void k_scatter(const int* __restrict__ idxs,
    int* __restrict__ cursor, int* __restrict__ order, int* __restrict__ inv)
{
  int t = blockIdx.x*blockDim.x + threadIdx.x;
#pragma unroll
  for(int k=0;k<2;k++){
    int s = 2*t+k;
    int e = idxs[s];
    int p = atomicAdd(&cursor[e],1);
    order[p]=s; inv[s]=p;
  }
}

// ======== FFN1 (R15-proven): h = silu(x@w1^T)*(x@w3^T), 128x128x2, BK=32 ========
__global__ __launch_bounds__(512) void k_ffn1(
    const __bf16* __restrict__ xb, const __bf16* __restrict__ w1b,
    const __bf16* __restrict__ w3b, const int* __restrict__ off,
    const int* __restrict__ mtp, const int* __restrict__ order,
    __bf16* __restrict__ h)
{
  __shared__ __align__(16) __bf16 lA [2][BM*BK];
  __shared__ __align__(16) __bf16 lB1[2][BM*BK];
  __shared__ __align__(16) __bf16 lB3[2][BM*BK];

  const int NT = HID/128;                // 22
  int wg = xcd_map(blockIdx.x, MAXMT*NT);
  int mt = wg / NT, nt = wg % NT;
  if (mt >= mtp[NE]) return;
  int e = 0;
  while (mt >= mtp[e+1]) e++;
  int row0    = off[e] + (mt - mtp[e])*BM;
  int row_end = off[e+1];
  int n0      = nt*128;

  int tid = threadIdx.x, lane = tid&63;
  int srow = tid>>2;
  int scol = ((tid&3) ^ ((srow>>1)&3))<<3;   // pre-swizzled source granule
  int arow = min(row0 + srow, row_end-1);
  int tok  = order[arow] >> 1;
  const __bf16* gA  = xb  + (size_t)tok*DIM + scol;
  const __bf16* gB1 = w1b + (size_t)e*HID*DIM + (size_t)(n0+srow)*DIM + scol;
  const __bf16* gB3 = w3b + (size_t)e*HID*DIM + (size_t)(n0+srow)*DIM + scol;
  int ldso = (tid>>6)<<9;                // wave * 512 elements (1KB)

  int wm = (tid>>6)>>2, wn = (tid>>6)&3; // 2x4 wave grid, wave tile 64x32 (x2 tensors)
  int fr = lane & 15, gq = lane>>4;

  f32x4 acc1[4][2], acc3[4][2];
#pragma unroll
  for(int m=0;m<4;m++)
#pragma unroll
    for(int n=0;n<2;n++){ acc1[m][n]=f32x4{0.f,0.f,0.f,0.f}; acc3[m][n]=f32x4{0.f,0.f,0.f,0.f}; }

  gld_lds16(gA,  &lA [0][ldso]);
  gld_lds16(gB1, &lB1[0][ldso]);
  gld_lds16(gB3, &lB3[0][ldso]);
  __syncthreads();

  const int NK = DIM/BK;                 // 32
  int buf=0;
  for(int kt=0; kt<NK; kt++){
    if(kt+1<NK){
      gld_lds16(gA  + (kt+1)*BK, &lA [buf^1][ldso]);
      gld_lds16(gB1 + (kt+1)*BK, &lB1[buf^1][ldso]);
      gld_lds16(gB3 + (kt+1)*BK, &lB3[buf^1][ldso]);
    }
    bf16x8 av[4], bv[2], cv[2];
#pragma unroll
    for(int m=0;m<4;m++) av[m]=*reinterpret_cast<const bf16x8*>(&lA[buf][SWZ(wm*64+m*16+fr, gq)]);
#pragma unroll
    for(int n=0;n<2;n++){
      bv[n]=*reinterpret_cast<const bf16x8*>(&lB1[buf][SWZ(wn*32+n*16+fr, gq)]);
      cv[n]=*reinterpret_cast<const bf16x8*>(&lB3[buf][SWZ(wn*32+n*16+fr, gq)]);
    }
#pragma unroll
    for(int m=0;m<4;m++)
#pragma unroll
      for(int n=0;n<2;n++){
        acc1[m][n]=MFMA(av[m],bv[n],acc1[m][n]);
        acc3[m][n]=MFMA(av[m],cv[n],acc3[m][n]);
      }
    __syncthreads();
    buf^=1;
  }

#pragma unroll
  for(int m=0;m<4;m++){
    int rbase = row0 + wm*64 + m*16 + (gq<<2);
#pragma unroll
    for(int r=0;r<4;r++){
      if(rbase+r < row_end){
        __bf16* hp = h + (size_t)(rbase+r)*HID + n0 + wn*32 + fr;
#pragma unroll
        for(int n=0;n<2;n++){
          float u = acc1[m][n][r], v = acc3[m][n][r];
          hp[n*16] = (__bf16)( (u/(1.f+__expf(-u))) * v );
        }
      }
    }
  }
}

// ======== FFN2 (R15-proven): ys = h @ w2^T, 128x128, 256 thr, dbuf ========
__global__ __launch_bounds__(256) void k_ffn2(
    const __bf16* __restrict__ h, const __bf16* __restrict__ w2b,
    const int* __restrict__ off, const int* __restrict__ mtp,
    __bf16* __restrict__ ys)
{
  __shared__ __align__(16) __bf16 lA[2][128*BK];    // 8 KB per buf
  __shared__ __align__(16) __bf16 lB[2][128*BK];

  const int NT = DIM/128;                // 8
  int wg = xcd_map(blockIdx.x, MAXMT*NT);
  int mt = wg / NT, nt = wg % NT;
  if (mt >= mtp[NE]) return;
  int e = 0;
  while (mt >= mtp[e+1]) e++;
  int row0    = off[e] + (mt - mtp[e])*BM;
  int row_end = off[e+1];
  int n0      = nt*128;

  int tid = threadIdx.x, lane = tid&63, wave = tid>>6;  // 4 waves
  int srow = tid>>2;                     // 0..63
  int scol = ((tid&3) ^ ((srow>>1)&3))<<3;   // same XOR phase valid for srow+64 (64%8==0)
  int hr0 = min(row0 + srow,      NSLOT-1);
  int hr1 = min(row0 + srow + 64, NSLOT-1);
  const __bf16* gA0 = h   + (size_t)hr0*HID + scol;
  const __bf16* gA1 = h   + (size_t)hr1*HID + scol;
  const __bf16* gB0 = w2b + (size_t)e*DIM*HID + (size_t)(n0+srow)*HID + scol;
  const __bf16* gB1 = w2b + (size_t)e*DIM*HID + (size_t)(n0+srow+64)*HID + scol;
  int ldso = wave<<9;                    // wave * 512 elements (1KB)

  int wm = wave>>1, wn = wave&1;         // 2x2 wave grid; wave tile 64(M)x64(N)
  int fr = lane&15, gq = lane>>4;

  f32x4 acc[4][4];
#pragma unroll
  for(int m=0;m<4;m++)
#pragma unroll
    for(int n=0;n<4;n++) acc[m][n]=f32x4{0.f,0.f,0.f,0.f};

  gld_lds16(gA0, &lA[0][ldso]);
  gld_lds16(gA1, &lA[0][2048+ldso]);
  gld_lds16(gB0, &lB[0][ldso]);
  gld_lds16(gB1, &lB[0][2048+ldso]);
  __syncthreads();

  const int NK = HID/BK;                 // 88
  int buf=0;
  for(int kt=0; kt<NK; kt++){
    if(kt+1<NK){
      gld_lds16(gA0 + (kt+1)*BK, &lA[buf^1][ldso]);
      gld_lds16(gA1 + (kt+1)*BK, &lA[buf^1][2048+ldso]);
      gld_lds16(gB0 + (kt+1)*BK, &lB[buf^1][ldso]);
      gld_lds16(gB1 + (kt+1)*BK, &lB[buf^1][2048+ldso]);
    }
    bf16x8 av[4], bv[4];
#pragma unroll
    for(int m=0;m<4;m++) av[m]=*reinterpret_cast<const bf16x8*>(&lA[buf][SWZ(wm*64+m*16+fr, gq)]);
#pragma unroll
    for(int n=0;n<4;n++) bv[n]=*reinterpret_cast<const bf16x8*>(&lB[buf][SWZ(wn*64+n*16+fr, gq)]);
#pragma unroll
    for(int m=0;m<4;m++)
#pragma unroll
      for(int n=0;n<4;n++)
        acc[m][n]=MFMA(av[m],bv[n],acc[m][n]);
    __syncthreads();
    buf^=1;
  }

  // epilogue: per-slot bf16 ys (no atomics)
#pragma unroll
  for(int m=0;m<4;m++){
    int rbase = row0 + wm*64 + m*16 + (gq<<2);
#pragma unroll
    for(int r=0;r<4;r++){
      if(rbase+r < row_end){
        __bf16* yp = ys + (size_t)(rbase+r)*DIM + n0 + wn*64 + fr;
#pragma unroll
        for(int n=0;n<4;n++) yp[n*16] = (__bf16)acc[m][n][r];
      }
    }
  }
}

// ---------------- weighted combine (fully overwrites y) ----------------
__global__ __launch_bounds__(256) void k_combine(
    const __bf16* __restrict__ ys, const int* __restrict__ inv,
    const float* __restrict__ wt, float* __restrict__ y)
{
  int t  = blockIdx.x;
  int p0 = inv[2*t], p1 = inv[2*t+1];
  float w0 = wt[2*t], w1v = wt[2*t+1];
  int d = threadIdx.x*4;
  const __bf16* r0 = ys + (size_t)p0*DIM + d;
  const __bf16* r1 = ys + (size_t)p1*DIM + d;
  f32x4 o;
#pragma unroll
  for(int j=0;j<4;j++) o[j] = w0*(float)r0[j] + w1v*(float)r1[j];
  *reinterpret_cast<f32x4*>(y + (size_t)t*DIM + d) = o;
}

// ---------------- launch ----------------
extern "C" void kernel_launch(void* const* d_in, const int* in_sizes, int n_in,
                              void* d_out, int out_size, void* d_ws, size_t ws_size,
                              hipStream_t stream)
{
  const float* x  = (const float*)d_in[0];
  const float* gw = (const float*)d_in[1];
  const float* w1 = (const float*)d_in[2];
  const float* w3 = (const float*)d_in[3];
  const float* w2 = (const float*)d_in[4];
  float* y = (float*)d_out;
  char* ws = (char*)d_ws;

  int*   off    = (int*)(ws + 64);
  int*   mtp    = (int*)(ws + 128);
  int*   cursor = (int*)(ws + 256);
  int*   idxs   = (int*)(ws + 320);
  float* wt     = (float*)(ws + 320 + 65536);
  int*   order  = (int*)(ws + 320 + 2*65536);
  int*   inv    = (int*)(ws + 320 + 3*65536);
  __bf16* h     = (__bf16*)(ws + 262464);
  __bf16* xb    = (__bf16*)(ws + 262464 + 92274688ull);
  __bf16* w1b   = (__bf16*)(ws + 262464 + 92274688ull + 16777216ull);
  __bf16* w3b   = (__bf16*)(ws + 262464 + 92274688ull + 16777216ull + 46137344ull);
  __bf16* w2b   = (__bf16*)(ws + 262464 + 92274688ull + 16777216ull + 2*46137344ull);
  __bf16* ysb   = w1b;   // dead after k_ffn1 -> reuse (33.5MB <= 46MB)

  k_cvtgate<<<GATEB + 3*CVTPB, 256, 0, stream>>>(x, gw, w1, w3, w2,
                                                 w1b, w3b, w2b, idxs, wt, xb);
  k_prep   <<<1, 256, 0, stream>>>(idxs, off, mtp, cursor);
  k_scatter<<<NTOK/256, 256, 0, stream>>>(idxs, cursor, order, inv);
  k_ffn1   <<<MAXMT*(HID/128), 512, 0, stream>>>(xb, w1b, w3b, off, mtp, order, h);
  k_ffn2   <<<MAXMT*(DIM/128), 256, 0, stream>>>(h, w2b, off, mtp, ysb);
  k_combine<<<NTOK, 256, 0, stream>>>(ysb, inv, wt, y);
}

// Round 17
// 614.604 us; speedup vs baseline: 1.3132x; 1.0022x over previous
//
#include <hip/hip_runtime.h>
#include <hip/hip_bf16.h>

#define NTOK 8192
#define DIM 1024
#define HID 2816
#define NE 8
#define NSLOT (NTOK*2)
#define BM 128
#define BK 32
#define MAXMT (NSLOT/BM + NE)   // 136 worst-case M-tiles @ BM=128

typedef float f32x4 __attribute__((ext_vector_type(4)));
typedef __bf16 bf16x8 __attribute__((ext_vector_type(8)));
typedef __bf16 bf16x4 __attribute__((ext_vector_type(4)));

#define MFMA(a,b,c) __builtin_amdgcn_mfma_f32_16x16x32_bf16(a,b,c,0,0,0)
// element index in a linear [rows][32] bf16 tile, XOR bank swizzle (R2-proven: 0 conflicts)
#define SWZ(r,g) (((r)<<5) + ((((g) ^ (((r)>>1)&3)))<<3))

__device__ __forceinline__ void cvt_st8(__bf16* d, f32x4 a, f32x4 b){
  bf16x8 v;
  v[0]=(__bf16)a.x; v[1]=(__bf16)a.y; v[2]=(__bf16)a.z; v[3]=(__bf16)a.w;
  v[4]=(__bf16)b.x; v[5]=(__bf16)b.y; v[6]=(__bf16)b.z; v[7]=(__bf16)b.w;
  *reinterpret_cast<bf16x8*>(d) = v;
}
__device__ __forceinline__ void gld_lds16(const void* g, void* l){
  __builtin_amdgcn_global_load_lds(
    (const __attribute__((address_space(1))) void*)g,
    (__attribute__((address_space(3))) void*)l, 16, 0, 0);
}
__device__ __forceinline__ int xcd_map(int orig, int nwg){
  int q = nwg>>3, rr = nwg&7, x = orig&7, o = orig>>3;
  return (x<rr ? x*(q+1) : rr*(q+1)+(x-rr)*q) + o;
}

// ======== fused gate + w1/w3 conversion (grid-section kernel) ========
#define GATEB (NTOK/8)              // 1024
#define CVTPB (NE*HID*DIM/16/256)   // 5632 blocks per tensor (256 thr, 16 f32/thr)
__global__ __launch_bounds__(256) void k_cvtgate(
    const float* __restrict__ x,  const float* __restrict__ gw,
    const float* __restrict__ s1, const float* __restrict__ s3,
    __bf16* __restrict__ d1, __bf16* __restrict__ d3,
    int* __restrict__ idxs, float* __restrict__ wt, __bf16* __restrict__ xb)
{
  int tid = threadIdx.x;
  if(blockIdx.x >= GATEB){
    // ---- w1/w3 conversion section (fat threads + NT loads) ----
    int cb  = blockIdx.x - GATEB;
    int seg = cb / CVTPB;
    size_t i = (size_t)(cb % CVTPB)*256 + tid;   // unit of 16 f32
    const float* src = (seg==0) ? s1 : s3;
    __bf16*      dst = (seg==0) ? d1 : d3;
    const f32x4* s = reinterpret_cast<const f32x4*>(src) + i*4;
    f32x4 a = __builtin_nontemporal_load(s);     // fp32 source is read-once
    f32x4 b = __builtin_nontemporal_load(s+1);
    f32x4 c = __builtin_nontemporal_load(s+2);
    f32x4 d = __builtin_nontemporal_load(s+3);
    cvt_st8(dst + i*16,     a, b);
    cvt_st8(dst + i*16 + 8, c, d);
    return;
  }

  // ---- gating section (R7-proven lane-parallel f64 dots) ----
  __shared__ double part[8][8][4];
  __shared__ double lg[8][8];

  int tl = tid>>5, e = (tid>>2)&7, q = tid&3;
  int t  = blockIdx.x*8 + tl;

  const f32x4* x4 = reinterpret_cast<const f32x4*>(x)  + (size_t)t*256 + q*64;
  const f32x4* g4 = reinterpret_cast<const f32x4*>(gw) + e*256 + q*64;

  double s0 = 0.0, s1d = 0.0;
#pragma unroll 4
  for(int j=0;j<64;j+=2){
    f32x4 a0 = x4[j],   b0 = g4[j];
    f32x4 a1 = x4[j+1], b1 = g4[j+1];
    s0  += (double)a0.x*b0.x + (double)a0.y*b0.y
         + (double)a0.z*b0.z + (double)a0.w*b0.w;
    s1d += (double)a1.x*b1.x + (double)a1.y*b1.y
         + (double)a1.z*b1.z + (double)a1.w*b1.w;
  }
  part[tl][e][q] = s0 + s1d;
  __syncthreads();
  if(q==0)
    lg[tl][e] = part[tl][e][0] + part[tl][e][1] + part[tl][e][2] + part[tl][e][3];
  __syncthreads();

  if(tid < 8){
    int tt = blockIdx.x*8 + tid;
    int i1=0; double m1=lg[tid][0];
#pragma unroll
    for(int k=1;k<NE;k++) if(lg[tid][k]>m1){ m1=lg[tid][k]; i1=k; }
    int i2=-1; double m2=-1e300;
#pragma unroll
    for(int k=0;k<NE;k++) if(k!=i1 && lg[tid][k]>m2){ m2=lg[tid][k]; i2=k; }
    float e2 = __expf((float)(m2-m1));
    float w0 = 1.f/(1.f+e2);
    idxs[2*tt]=i1; idxs[2*tt+1]=i2;
    wt[2*tt]=w0;   wt[2*tt+1]=e2*w0;
  }

  const f32x4* xs = reinterpret_cast<const f32x4*>(x) + (size_t)blockIdx.x*2048;
  __bf16* xo = xb + (size_t)blockIdx.x*8192;
#pragma unroll
  for(int k=0;k<4;k++){
    int c = k*256 + tid;
    cvt_st8(xo + (size_t)c*8, xs[2*c], xs[2*c+1]);
  }
}

// ---- prep: histogram idxs -> cnt, then serial prefix (R16-proven) ----
__global__ __launch_bounds__(256) void k_prep(const int* __restrict__ idxs,
    int* __restrict__ off, int* __restrict__ mtp, int* __restrict__ cursor)
{
  __shared__ int hist[NE];
  int tid = threadIdx.x;
  if(tid < NE) hist[tid] = 0;
  __syncthreads();
  int local[NE] = {0,0,0,0,0,0,0,0};
  for(int k=0;k<NSLOT/256;k++){
    int e = idxs[tid*(NSLOT/256) + k];
    local[e]++;
  }
#pragma unroll
  for(int e=0;e<NE;e++) if(local[e]) atomicAdd(&hist[e], local[e]);
  __syncthreads();
  if(tid==0){
    int o=0, m=0; off[0]=0; mtp[0]=0;
    for(int e=0;e<NE;e++){
      cursor[e]=o; o += hist[e]; off[e+1]=o;
      m += (hist[e]+BM-1)/BM;  mtp[e+1]=m;
    }
  }
}

__global__ __launch_bounds__(256) void k_scatter(const int* __restrict__ idxs,
    int* __restrict__ cursor, int* __restrict__ order, int* __restrict__ inv)
{
  int t = blockIdx.x*blockDim.x + threadIdx.x;
#pragma unroll
  for(int k=0;k<2;k++){
    int s = 2*t+k;
    int e = idxs[s];
    int p = atomicAdd(&cursor[e],1);
    order[p]=s; inv[s]=p;
  }
}

// ======== FFN1 (R15-proven body) + w2-cvt tail section ========
#define FFN1B (MAXMT*(HID/128))     // 2992 GEMM blocks
#define CVT2B (NE*DIM*HID/16/512)   // 2816 cvt blocks (512 thr, 16 f32/thr)
__global__ __launch_bounds__(512) void k_ffn1(
    const __bf16* __restrict__ xb, const __bf16* __restrict__ w1b,
    const __bf16* __restrict__ w3b, const int* __restrict__ off,
    const int* __restrict__ mtp, const int* __restrict__ order,
    __bf16* __restrict__ h, const float* __restrict__ w2src,
    __bf16* __restrict__ w2b)
{
  __shared__ __align__(16) __bf16 lA [2][BM*BK];
  __shared__ __align__(16) __bf16 lB1[2][BM*BK];
  __shared__ __align__(16) __bf16 lB3[2][BM*BK];

  int tid = threadIdx.x;
  if(blockIdx.x >= FFN1B){
    // ---- w2 fp32->bf16 section: runs in ffn1's tail (BW idle there);
    //      w2b is complete before kernel end -> safe for ffn2. ----
    size_t i = (size_t)(blockIdx.x - FFN1B)*512 + tid;   // unit of 16 f32
    const f32x4* s = reinterpret_cast<const f32x4*>(w2src) + i*4;
    f32x4 a = __builtin_nontemporal_load(s);
    f32x4 b = __builtin_nontemporal_load(s+1);
    f32x4 c = __builtin_nontemporal_load(s+2);
    f32x4 d = __builtin_nontemporal_load(s+3);
    cvt_st8(w2b + i*16,     a, b);
    cvt_st8(w2b + i*16 + 8, c, d);
    return;
  }

  const int NT = HID/128;                // 22
  int wg = xcd_map(blockIdx.x, FFN1B);
  int mt = wg / NT, nt = wg % NT;
  if (mt >= mtp[NE]) return;
  int e = 0;
  while (mt >= mtp[e+1]) e++;
  int row0    = off[e] + (mt - mtp[e])*BM;
  int row_end = off[e+1];
  int n0      = nt*128;

  int lane = tid&63;
  int srow = tid>>2;
  int scol = ((tid&3) ^ ((srow>>1)&3))<<3;   // pre-swizzled source granule
  int arow = min(row0 + srow, row_end-1);
  int tok  = order[arow] >> 1;
  const __bf16* gA  = xb  + (size_t)tok*DIM + scol;
  const __bf16* gB1 = w1b + (size_t)e*HID*DIM + (size_t)(n0+srow)*DIM + scol;
  const __bf16* gB3 = w3b + (size_t)e*HID*DIM + (size_t)(n0+srow)*DIM + scol;
  int ldso = (tid>>6)<<9;                // wave * 512 elements (1KB)

  int wm = (tid>>6)>>2, wn = (tid>>6)&3; // 2x4 wave grid, wave tile 64x32 (x2 tensors)
  int fr = lane & 15, gq = lane>>4;

  f32x4 acc1[4][2], acc3[4][2];
#pragma unroll
  for(int m=0;m<4;m++)
#pragma unroll
    for(int n=0;n<2;n++){ acc1[m][n]=f32x4{0.f,0.f,0.f,0.f}; acc3[m][n]=f32x4{0.f,0.f,0.f,0.f}; }

  gld_lds16(gA,  &lA [0][ldso]);
  gld_lds16(gB1, &lB1[0][ldso]);
  gld_lds16(gB3, &lB3[0][ldso]);
  __syncthreads();

  const int NK = DIM/BK;                 // 32
  int buf=0;
  for(int kt=0; kt<NK; kt++){
    if(kt+1<NK){
      gld_lds16(gA  + (kt+1)*BK, &lA [buf^1][ldso]);
      gld_lds16(gB1 + (kt+1)*BK, &lB1[buf^1][ldso]);
      gld_lds16(gB3 + (kt+1)*BK, &lB3[buf^1][ldso]);
    }
    bf16x8 av[4], bv[2], cv[2];
#pragma unroll
    for(int m=0;m<4;m++) av[m]=*reinterpret_cast<const bf16x8*>(&lA[buf][SWZ(wm*64+m*16+fr, gq)]);
#pragma unroll
    for(int n=0;n<2;n++){
      bv[n]=*reinterpret_cast<const bf16x8*>(&lB1[buf][SWZ(wn*32+n*16+fr, gq)]);
      cv[n]=*reinterpret_cast<const bf16x8*>(&lB3[buf][SWZ(wn*32+n*16+fr, gq)]);
    }
#pragma unroll
    for(int m=0;m<4;m++)
#pragma unroll
      for(int n=0;n<2;n++){
        acc1[m][n]=MFMA(av[m],bv[n],acc1[m][n]);
        acc3[m][n]=MFMA(av[m],cv[n],acc3[m][n]);
      }
    __syncthreads();
    buf^=1;
  }

#pragma unroll
  for(int m=0;m<4;m++){
    int rbase = row0 + wm*64 + m*16 + (gq<<2);
#pragma unroll
    for(int r=0;r<4;r++){
      if(rbase+r < row_end){
        __bf16* hp = h + (size_t)(rbase+r)*HID + n0 + wn*32 + fr;
#pragma unroll
        for(int n=0;n<2;n++){
          float u = acc1[m][n][r], v = acc3[m][n][r];
          hp[n*16] = (__bf16)( (u/(1.f+__expf(-u))) * v );
        }
      }
    }
  }
}

// ======== FFN2 (R15-proven): ys = h @ w2^T, 128x128, 256 thr, dbuf ========
__global__ __launch_bounds__(256) void k_ffn2(
    const __bf16* __restrict__ h, const __bf16* __restrict__ w2b,
    const int* __restrict__ off, const int* __restrict__ mtp,
    __bf16* __restrict__ ys)
{
  __shared__ __align__(16) __bf16 lA[2][128*BK];    // 8 KB per buf
  __shared__ __align__(16) __bf16 lB[2][128*BK];

  const int NT = DIM/128;                // 8
  int wg = xcd_map(blockIdx.x, MAXMT*NT);
  int mt = wg / NT, nt = wg % NT;
  if (mt >= mtp[NE]) return;
  int e = 0;
  while (mt >= mtp[e+1]) e++;
  int row0    = off[e] + (mt - mtp[e])*BM;
  int row_end = off[e+1];
  int n0      = nt*128;

  int tid = threadIdx.x, lane = tid&63, wave = tid>>6;  // 4 waves
  int srow = tid>>2;                     // 0..63
  int scol = ((tid&3) ^ ((srow>>1)&3))<<3;   // same XOR phase valid for srow+64 (64%8==0)
  int hr0 = min(row0 + srow,      NSLOT-1);
  int hr1 = min(row0 + srow + 64, NSLOT-1);
  const __bf16* gA0 = h   + (size_t)hr0*HID + scol;
  const __bf16* gA1 = h   + (size_t)hr1*HID + scol;
  const __bf16* gB0 = w2b + (size_t)e*DIM*HID + (size_t)(n0+srow)*HID + scol;
  const __bf16* gB1 = w2b + (size_t)e*DIM*HID + (size_t)(n0+srow+64)*HID + scol;
  int ldso = wave<<9;                    // wave * 512 elements (1KB)

  int wm = wave>>1, wn = wave&1;         // 2x2 wave grid; wave tile 64(M)x64(N)
  int fr = lane&15, gq = lane>>4;

  f32x4 acc[4][4];
#pragma unroll
  for(int m=0;m<4;m++)
#pragma unroll
    for(int n=0;n<4;n++) acc[m][n]=f32x4{0.f,0.f,0.f,0.f};

  gld_lds16(gA0, &lA[0][ldso]);
  gld_lds16(gA1, &lA[0][2048+ldso]);
  gld_lds16(gB0, &lB[0][ldso]);
  gld_lds16(gB1, &lB[0][2048+ldso]);
  __syncthreads();

  const int NK = HID/BK;                 // 88
  int buf=0;
  for(int kt=0; kt<NK; kt++){
    if(kt+1<NK){
      gld_lds16(gA0 + (kt+1)*BK, &lA[buf^1][ldso]);
      gld_lds16(gA1 + (kt+1)*BK, &lA[buf^1][2048+ldso]);
      gld_lds16(gB0 + (kt+1)*BK, &lB[buf^1][ldso]);
      gld_lds16(gB1 + (kt+1)*BK, &lB[buf^1][2048+ldso]);
    }
    bf16x8 av[4], bv[4];
#pragma unroll
    for(int m=0;m<4;m++) av[m]=*reinterpret_cast<const bf16x8*>(&lA[buf][SWZ(wm*64+m*16+fr, gq)]);
#pragma unroll
    for(int n=0;n<4;n++) bv[n]=*reinterpret_cast<const bf16x8*>(&lB[buf][SWZ(wn*64+n*16+fr, gq)]);
#pragma unroll
    for(int m=0;m<4;m++)
#pragma unroll
      for(int n=0;n<4;n++)
        acc[m][n]=MFMA(av[m],bv[n],acc[m][n]);
    __syncthreads();
    buf^=1;
  }

  // epilogue: per-slot bf16 ys (no atomics)
#pragma unroll
  for(int m=0;m<4;m++){
    int rbase = row0 + wm*64 + m*16 + (gq<<2);
#pragma unroll
    for(int r=0;r<4;r++){
      if(rbase+r < row_end){
        __bf16* yp = ys + (size_t)(rbase+r)*DIM + n0 + wn*64 + fr;
#pragma unroll
        for(int n=0;n<4;n++) yp[n*16] = (__bf16)acc[m][n][r];
      }
    }
  }
}

// ---------------- weighted combine (fully overwrites y) ----------------
__global__ __launch_bounds__(256) void k_combine(
    const __bf16* __restrict__ ys, const int* __restrict__ inv,
    const float* __restrict__ wt, float* __restrict__ y)
{
  int t  = blockIdx.x;
  int p0 = inv[2*t], p1 = inv[2*t+1];
  float w0 = wt[2*t], w1v = wt[2*t+1];
  int d = threadIdx.x*4;
  const __bf16* r0 = ys + (size_t)p0*DIM + d;
  const __bf16* r1 = ys + (size_t)p1*DIM + d;
  f32x4 o;
#pragma unroll
  for(int j=0;j<4;j++) o[j] = w0*(float)r0[j] + w1v*(float)r1[j];
  *reinterpret_cast<f32x4*>(y + (size_t)t*DIM + d) = o;
}

// ---------------- launch ----------------
extern "C" void kernel_launch(void* const* d_in, const int* in_sizes, int n_in,
                              void* d_out, int out_size, void* d_ws, size_t ws_size,
                              hipStream_t stream)
{
  const float* x  = (const float*)d_in[0];
  const float* gw = (const float*)d_in[1];
  const float* w1 = (const float*)d_in[2];
  const float* w3 = (const float*)d_in[3];
  const float* w2 = (const float*)d_in[4];
  float* y = (float*)d_out;
  char* ws = (char*)d_ws;

  int*   off    = (int*)(ws + 64);
  int*   mtp    = (int*)(ws + 128);
  int*   cursor = (int*)(ws + 256);
  int*   idxs   = (int*)(ws + 320);
  float* wt     = (float*)(ws + 320 + 65536);
  int*   order  = (int*)(ws + 320 + 2*65536);
  int*   inv    = (int*)(ws + 320 + 3*65536);
  __bf16* h     = (__bf16*)(ws + 262464);
  __bf16* xb    = (__bf16*)(ws + 262464 + 92274688ull);
  __bf16* w1b   = (__bf16*)(ws + 262464 + 92274688ull + 16777216ull);
  __bf16* w3b   = (__bf16*)(ws + 262464 + 92274688ull + 16777216ull + 46137344ull);
  __bf16* w2b   = (__bf16*)(ws + 262464 + 92274688ull + 16777216ull + 2*46137344ull);
  __bf16* ysb   = w1b;   // dead after k_ffn1 -> reuse (33.5MB <= 46MB)

  k_cvtgate<<<GATEB + 2*CVTPB, 256, 0, stream>>>(x, gw, w1, w3,
                                                 w1b, w3b, idxs, wt, xb);
  k_prep   <<<1, 256, 0, stream>>>(idxs, off, mtp, cursor);
  k_scatter<<<NTOK/256, 256, 0, stream>>>(idxs, cursor, order, inv);
  k_ffn1   <<<FFN1B + CVT2B, 512, 0, stream>>>(xb, w1b, w3b, off, mtp, order,
                                               h, w2, w2b);
  k_ffn2   <<<MAXMT*(DIM/128), 256, 0, stream>>>(h, w2b, off, mtp, ysb);
  k_combine<<<NTOK, 256, 0, stream>>>(ysb, inv, wt, y);
}